// Round 1
// baseline (209.246 us; speedup 1.0000x reference)
//
#include <hip/hip_runtime.h>

// YOLO-v1 loss, S=14, B=2, C=20, NCH=30, Nb=4096.
// Memory-bound: 2 × 96.3 MB fp32 read -> scalar. Thread-per-cell, float2 loads.

#define S_GRID 14
#define NB 4096
#define NCELL (NB * S_GRID * S_GRID)   // 802816 = 3136 * 256
#define NCH 30
#define NBLOCKS (NCELL / 256)          // 3136

__global__ __launch_bounds__(256) void yolo_loss_partial(
    const float* __restrict__ pred, const float* __restrict__ target,
    float* __restrict__ partial)
{
    const int cell = blockIdx.x * 256 + threadIdx.x;
    float loss = 0.0f;

    {
        float p[NCH], t[NCH];
        const float2* p2 = (const float2*)(pred + (size_t)cell * NCH);
        const float2* t2 = (const float2*)(target + (size_t)cell * NCH);
#pragma unroll
        for (int i = 0; i < NCH / 2; ++i) {
            float2 a = p2[i]; p[2 * i] = a.x; p[2 * i + 1] = a.y;
            float2 b = t2[i]; t[2 * i] = b.x; t[2 * i + 1] = b.y;
        }

        const float t4 = t[4];
        const bool obj = (t4 > 0.0f);

        // no-object confidence loss over both box slots
        float dn0 = p[4] - t[4];
        float dn1 = p[9] - t[9];
        float noobj_l = (t4 == 0.0f) ? (dn0 * dn0 + dn1 * dn1) : 0.0f;

        // target box (slot 0) corners
        const float invS = 1.0f / 14.0f;
        float tcx = t[0] * invS, tcy = t[1] * invS;
        float tx1 = tcx - 0.5f * t[2], ty1 = tcy - 0.5f * t[3];
        float tx2 = tcx + 0.5f * t[2], ty2 = tcy + 0.5f * t[3];
        float area_t = (tx2 - tx1) * (ty2 - ty1);

        float iou[2];
#pragma unroll
        for (int b = 0; b < 2; ++b) {
            const float* pb = p + 5 * b;
            float cx = pb[0] * invS, cy = pb[1] * invS;
            float x1 = cx - 0.5f * pb[2], y1 = cy - 0.5f * pb[3];
            float x2 = cx + 0.5f * pb[2], y2 = cy + 0.5f * pb[3];
            float lx = fmaxf(x1, tx1), ly = fmaxf(y1, ty1);
            float rx = fminf(x2, tx2), ry = fminf(y2, ty2);
            float wx = fmaxf(rx - lx, 0.0f), wy = fmaxf(ry - ly, 0.0f);
            float inter = wx * wy;
            float area_p = (x2 - x1) * (y2 - y1);
            iou[b] = inter / (area_p + area_t - inter);
        }

        // jnp.argmax picks first max -> box 1 only on strict >
        int r = (iou[1] > iou[0]) ? 1 : 0;
        float max_iou = fmaxf(iou[0], iou[1]);

        if (obj) {
            const float* pr = p + 5 * r;
            const float* tr = t + 5 * r;
            float dx = pr[0] - tr[0], dy = pr[1] - tr[1];
            float lxy = dx * dx + dy * dy;
            float dw = sqrtf(pr[2]) - sqrtf(tr[2]);
            float dh = sqrtf(pr[3]) - sqrtf(tr[3]);
            float lwh = dw * dw + dh * dh;
            float dob = pr[4] - max_iou;
            float lob = dob * dob;
            float lcls = 0.0f;
#pragma unroll
            for (int c = 10; c < 30; ++c) {
                float d = p[c] - t[c];
                lcls += d * d;
            }
            loss = 5.0f * (lxy + lwh) + lob + lcls;
        }
        loss += 0.5f * noobj_l;
    }

    // wave (64-lane) shuffle reduce, then cross-wave via LDS
    float v = loss;
#pragma unroll
    for (int off = 32; off > 0; off >>= 1)
        v += __shfl_down(v, off, 64);

    __shared__ float red[4];
    const int lane = threadIdx.x & 63;
    const int wid = threadIdx.x >> 6;
    if (lane == 0) red[wid] = v;
    __syncthreads();
    if (threadIdx.x == 0)
        partial[blockIdx.x] = red[0] + red[1] + red[2] + red[3];
}

__global__ __launch_bounds__(256) void yolo_loss_finalize(
    const float* __restrict__ partial, float* __restrict__ out)
{
    double s = 0.0;
    for (int i = threadIdx.x; i < NBLOCKS; i += 256)
        s += (double)partial[i];

    __shared__ double sh[256];
    sh[threadIdx.x] = s;
    __syncthreads();
#pragma unroll
    for (int step = 128; step > 0; step >>= 1) {
        if (threadIdx.x < step) sh[threadIdx.x] += sh[threadIdx.x + step];
        __syncthreads();
    }
    if (threadIdx.x == 0)
        out[0] = (float)(sh[0] / (double)NB);
}

extern "C" void kernel_launch(void* const* d_in, const int* in_sizes, int n_in,
                              void* d_out, int out_size, void* d_ws, size_t ws_size,
                              hipStream_t stream) {
    const float* pred = (const float*)d_in[0];
    const float* target = (const float*)d_in[1];
    float* out = (float*)d_out;
    float* partial = (float*)d_ws;   // NBLOCKS floats = 12.5 KB scratch

    yolo_loss_partial<<<NBLOCKS, 256, 0, stream>>>(pred, target, partial);
    yolo_loss_finalize<<<1, 256, 0, stream>>>(partial, out);
}

// Round 2
// 206.517 us; speedup vs baseline: 1.0132x; 1.0132x over previous
//
#include <hip/hip_runtime.h>

// YOLO-v1 loss, S=14, B=2, C=20, NCH=30, Nb=4096.
// Memory-bound: 2 x 96.3 MB fp32 read -> scalar.
// R2: coalesced staging via global_load_lds (1024 B/wave-instr), compute from LDS.

#define S_GRID 14
#define NB 4096
#define NCELL (NB * S_GRID * S_GRID)   // 802816 = 3136 * 256
#define NCH 30
#define CELLS_PER_BLOCK 256
#define NBLOCKS (NCELL / CELLS_PER_BLOCK)   // 3136
#define FLOATS_PER_BLOCK (CELLS_PER_BLOCK * NCH)   // 7680 floats = 1920 float4

#define GLOBAL_AS __attribute__((address_space(1)))
#define LDS_AS    __attribute__((address_space(3)))

__device__ __forceinline__ void async_copy16(const float* g, float* l) {
    __builtin_amdgcn_global_load_lds((const GLOBAL_AS void*)g, (LDS_AS void*)l,
                                     16, 0, 0);
}

__global__ __launch_bounds__(256) void yolo_loss_partial(
    const float* __restrict__ pred, const float* __restrict__ target,
    float* __restrict__ partial)
{
    __shared__ float ps[FLOATS_PER_BLOCK];   // 30 KB
    __shared__ float ts[FLOATS_PER_BLOCK];   // 30 KB

    const int tid = threadIdx.x;
    const size_t base = (size_t)blockIdx.x * FLOATS_PER_BLOCK;

    // Stage 1920 float4 per tensor, 256 lanes x 16 B = 4 KB per round.
    // Rounds 0..6 full; round 7 half (threads 0..127).
#pragma unroll
    for (int r = 0; r < 8; ++r) {
        int idx = r * 256 + tid;               // float4 index
        if (idx < FLOATS_PER_BLOCK / 4) {
            async_copy16(pred + base + (size_t)idx * 4, ps + idx * 4);
            async_copy16(target + base + (size_t)idx * 4, ts + idx * 4);
        }
    }
    __syncthreads();   // compiler emits s_waitcnt vmcnt(0) before s_barrier

    float loss;
    {
        float p[NCH], t[NCH];
        const float2* p2 = (const float2*)(ps + tid * NCH);  // 120 B stride, 8B aligned
        const float2* t2 = (const float2*)(ts + tid * NCH);
#pragma unroll
        for (int i = 0; i < NCH / 2; ++i) {
            float2 a = p2[i]; p[2 * i] = a.x; p[2 * i + 1] = a.y;
            float2 b = t2[i]; t[2 * i] = b.x; t[2 * i + 1] = b.y;
        }

        const float t4 = t[4];
        const bool obj = (t4 > 0.0f);

        // no-object confidence loss over both box slots
        float dn0 = p[4] - t[4];
        float dn1 = p[9] - t[9];
        float noobj_l = (t4 == 0.0f) ? (dn0 * dn0 + dn1 * dn1) : 0.0f;

        // target box (slot 0) corners
        const float invS = 1.0f / 14.0f;
        float tcx = t[0] * invS, tcy = t[1] * invS;
        float tx1 = tcx - 0.5f * t[2], ty1 = tcy - 0.5f * t[3];
        float tx2 = tcx + 0.5f * t[2], ty2 = tcy + 0.5f * t[3];
        float area_t = (tx2 - tx1) * (ty2 - ty1);

        float iou[2];
#pragma unroll
        for (int b = 0; b < 2; ++b) {
            const float* pb = p + 5 * b;
            float cx = pb[0] * invS, cy = pb[1] * invS;
            float x1 = cx - 0.5f * pb[2], y1 = cy - 0.5f * pb[3];
            float x2 = cx + 0.5f * pb[2], y2 = cy + 0.5f * pb[3];
            float lx = fmaxf(x1, tx1), ly = fmaxf(y1, ty1);
            float rx = fminf(x2, tx2), ry = fminf(y2, ty2);
            float wx = fmaxf(rx - lx, 0.0f), wy = fmaxf(ry - ly, 0.0f);
            float inter = wx * wy;
            float area_p = (x2 - x1) * (y2 - y1);
            iou[b] = inter / (area_p + area_t - inter);
        }

        // jnp.argmax picks first max -> box 1 only on strict >
        int r = (iou[1] > iou[0]) ? 1 : 0;
        float max_iou = fmaxf(iou[0], iou[1]);

        float obj_l = 0.0f;
        if (obj) {
            const float* pr = p + 5 * r;
            const float* tr = t + 5 * r;
            float dx = pr[0] - tr[0], dy = pr[1] - tr[1];
            float lxy = dx * dx + dy * dy;
            float dw = sqrtf(pr[2]) - sqrtf(tr[2]);
            float dh = sqrtf(pr[3]) - sqrtf(tr[3]);
            float lwh = dw * dw + dh * dh;
            float dob = pr[4] - max_iou;
            float lob = dob * dob;
            float lcls = 0.0f;
#pragma unroll
            for (int c = 10; c < 30; ++c) {
                float d = p[c] - t[c];
                lcls += d * d;
            }
            obj_l = 5.0f * (lxy + lwh) + lob + lcls;
        }
        loss = obj_l + 0.5f * noobj_l;
    }

    // wave (64-lane) shuffle reduce, then cross-wave via LDS
    float v = loss;
#pragma unroll
    for (int off = 32; off > 0; off >>= 1)
        v += __shfl_down(v, off, 64);

    __shared__ float red[4];
    const int lane = threadIdx.x & 63;
    const int wid = threadIdx.x >> 6;
    if (lane == 0) red[wid] = v;
    __syncthreads();
    if (threadIdx.x == 0)
        partial[blockIdx.x] = red[0] + red[1] + red[2] + red[3];
}

__global__ __launch_bounds__(256) void yolo_loss_finalize(
    const float* __restrict__ partial, float* __restrict__ out)
{
    double s = 0.0;
    for (int i = threadIdx.x; i < NBLOCKS; i += 256)
        s += (double)partial[i];

    __shared__ double sh[256];
    sh[threadIdx.x] = s;
    __syncthreads();
#pragma unroll
    for (int step = 128; step > 0; step >>= 1) {
        if (threadIdx.x < step) sh[threadIdx.x] += sh[threadIdx.x + step];
        __syncthreads();
    }
    if (threadIdx.x == 0)
        out[0] = (float)(sh[0] / (double)NB);
}

extern "C" void kernel_launch(void* const* d_in, const int* in_sizes, int n_in,
                              void* d_out, int out_size, void* d_ws, size_t ws_size,
                              hipStream_t stream) {
    const float* pred = (const float*)d_in[0];
    const float* target = (const float*)d_in[1];
    float* out = (float*)d_out;
    float* partial = (float*)d_ws;   // NBLOCKS floats = 12.5 KB scratch

    yolo_loss_partial<<<NBLOCKS, 256, 0, stream>>>(pred, target, partial);
    yolo_loss_finalize<<<1, 256, 0, stream>>>(partial, out);
}